// Round 3
// baseline (389993.140 us; speedup 1.0000x reference)
//
#include <hip/hip_runtime.h>
#include <hip/hip_cooperative_groups.h>
#include <cstddef>

namespace cg = cooperative_groups;

__device__ __forceinline__ float sigmoidf_(float x) {
    return 1.0f / (1.0f + __expf(-x));
}

#define FMA4(a4, w, x) \
    do { a4.x += (w).x*(x).x; a4.y += (w).y*(x).y; a4.z += (w).z*(x).z; a4.w += (w).w*(x).w; } while (0)

// ---------------- Prenet: p2 = relu(relu(prev @ W1^T) @ W2^T) ----------------
// one (t,b) row per block; 256 threads; p2 stored time-major [T][B][256]
__global__ __launch_bounds__(256) void prenet_kernel(
    const float* __restrict__ y_mels,   // [B][T][80]
    const float* __restrict__ W1,       // [256][80]
    const float* __restrict__ W2,       // [256][256]
    float* __restrict__ p2,             // [T][B][256]
    int T)
{
    const int rt = blockIdx.x;           // t*32 + b
    const int t = rt >> 5, b = rt & 31;
    const int j = threadIdx.x;           // 0..255
    __shared__ float prev[80];
    __shared__ float p1[256];
    if (j < 80) prev[j] = (t == 0) ? 0.0f : y_mels[((size_t)b * T + (t - 1)) * 80 + j];
    __syncthreads();
    float acc = 0.0f;
    const float* w1r = W1 + j * 80;
    #pragma unroll
    for (int k = 0; k < 80; k += 4) {
        float4 w = *(const float4*)(w1r + k);
        float4 x = *(const float4*)(&prev[k]);
        acc += w.x * x.x + w.y * x.y + w.z * x.z + w.w * x.w;
    }
    p1[j] = fmaxf(acc, 0.0f);
    __syncthreads();
    float4 a4 = make_float4(0.f, 0.f, 0.f, 0.f);
    const float* w2r = W2 + j * 256;
    #pragma unroll 8
    for (int k = 0; k < 256; k += 4) {
        float4 w = *(const float4*)(w2r + k);
        float4 x = *(const float4*)(&p1[k]);
        FMA4(a4, w, x);
    }
    p2[(size_t)rt * 256 + j] = fmaxf((a4.x + a4.y) + (a4.z + a4.w), 0.0f);
}

// ------------- Projection, memory part: out[b,t,o] = bp[o] + mem[b,t,:]·Wp[o,1024:] -------------
__global__ __launch_bounds__(128) void proj_mem_kernel(
    const float* __restrict__ memory, // [B][T][512]
    const float* __restrict__ Wp,     // [80][1536]
    const float* __restrict__ bp,     // [80]
    float* __restrict__ out,          // [B][T][80]
    int T)
{
    const int rt = blockIdx.x;          // b*T + t (batch-major, matches memory/out layout)
    const int tid = threadIdx.x;
    __shared__ float xm[512];
    for (int k = tid * 4; k < 512; k += 128 * 4)
        *(float4*)(&xm[k]) = *(const float4*)(memory + (size_t)rt * 512 + k);
    __syncthreads();
    if (tid < 80) {
        const float* wr = Wp + tid * 1536 + 1024;
        float4 a4 = make_float4(0.f, 0.f, 0.f, 0.f);
        #pragma unroll 8
        for (int k = 0; k < 512; k += 4) {
            float4 w = *(const float4*)(wr + k);
            float4 x = *(const float4*)(&xm[k]);
            FMA4(a4, w, x);
        }
        out[(size_t)rt * 80 + tid] = bp[tid] + (a4.x + a4.y) + (a4.z + a4.w);
    }
}

// ---------------- Fused 2-layer LSTM scan + projection epilogue (cooperative) ----------------
// grid = 256 blocks x 512 threads. Block bk owns cell indices [bk*4, bk*4+4) of BOTH layers.
// Thread (b, jl): one gate dot product per layer per step. jl = gate*4 + jo.
// Phase P (overlapped): 32-lane groups compute out[b,t-1,:] += h1[t-1]·Wp[:, :1024]^T.
__global__ __launch_bounds__(512) void fused_scan(
    const float* __restrict__ p2,     // [T][B][256] time-major
    const float* __restrict__ memory, // [B][T][512]
    const float* __restrict__ w_ih0,  // [4096][768]
    const float* __restrict__ w_hh0,  // [4096][1024]
    const float* __restrict__ b_ih0,
    const float* __restrict__ b_hh0,
    const float* __restrict__ w_ih1,  // [4096][1024]
    const float* __restrict__ w_hh1,  // [4096][1024]
    const float* __restrict__ b_ih1,
    const float* __restrict__ b_hh1,
    const float* __restrict__ Wp,     // [80][1536]
    float* __restrict__ h0_buf,       // [2][B][1024] ping-pong
    float* __restrict__ h1_buf,       // [2][B][1024] ping-pong
    float* __restrict__ out,          // [B][T][80], pre-initialized with memory part
    int T)
{
    const int B = 32, H = 1024;
    const int bk = blockIdx.x;        // 0..255
    const int tid = threadIdx.x;
    const int jl = tid & 15;          // gate*4 + jo
    const int b  = tid >> 4;          // 0..31
    const int gate = jl >> 2;
    const int jo = jl & 3;
    const int j = gate * H + bk * 4 + jo;

    __shared__ float gl[32][16];      // gate exchange
    __shared__ float cst0[32][4];     // layer-0 cell state slice
    __shared__ float cst1[32][4];     // layer-1 cell state slice
    if (tid < 128) { cst0[tid >> 2][tid & 3] = 0.0f; cst1[tid >> 2][tid & 3] = 0.0f; }

    const float bias0 = b_ih0[j] + b_hh0[j];
    const float bias1 = b_ih1[j] + b_hh1[j];
    const float* wi0 = w_ih0 + (size_t)j * 768;
    const float* wh0 = w_hh0 + (size_t)j * 1024;
    const float* wi1 = w_ih1 + (size_t)j * 1024;
    const float* wh1 = w_hh1 + (size_t)j * 1024;

    // projection assignment: 32-lane group per (pb, po) output scalar
    const int gid = bk * 16 + (tid >> 5);   // 0..4095; active if < 2560
    const int lane = tid & 31;
    const int pb = gid / 80;
    const int po = gid - pb * 80;
    const float* wp_row = Wp + po * 1536;   // h-part: first 1024

    cg::grid_group grid = cg::this_grid();
    __syncthreads();

    for (int t = 0; t < T; ++t) {
        // ---- Phase P: projection h-part for timestep t-1 (h1[t-1] is grid-synced) ----
        if (t > 0 && gid < 2560) {
            const float* hrow = h1_buf + ((size_t)((t - 1) & 1) * B + pb) * H;
            float4 s4 = make_float4(0.f, 0.f, 0.f, 0.f);
            #pragma unroll
            for (int i = 0; i < 8; ++i) {
                const int k = lane * 4 + i * 128;
                float4 w = *(const float4*)(wp_row + k);
                float4 x = *(const float4*)(hrow + k);
                FMA4(s4, w, x);
            }
            float s = (s4.x + s4.y) + (s4.z + s4.w);
            s += __shfl_xor(s, 16); s += __shfl_xor(s, 8);
            s += __shfl_xor(s, 4);  s += __shfl_xor(s, 2); s += __shfl_xor(s, 1);
            if (lane == 0) out[((size_t)pb * T + (t - 1)) * 80 + po] += s;
        }

        // ---- Phase A: layer-0 gates ----
        {
            float4 a4 = make_float4(0.f, 0.f, 0.f, 0.f);
            const float* xr = p2 + ((size_t)t * B + b) * 256;
            #pragma unroll 4
            for (int k = 0; k < 256; k += 4) {
                float4 w = *(const float4*)(wi0 + k);
                float4 x = *(const float4*)(xr + k);
                FMA4(a4, w, x);
            }
            const float* mr = memory + ((size_t)b * T + t) * 512;
            const float* wm = wi0 + 256;
            #pragma unroll 4
            for (int k = 0; k < 512; k += 4) {
                float4 w = *(const float4*)(wm + k);
                float4 x = *(const float4*)(mr + k);
                FMA4(a4, w, x);
            }
            if (t > 0) {
                const float* hr = h0_buf + ((size_t)((t - 1) & 1) * B + b) * H;
                #pragma unroll 4
                for (int k = 0; k < 1024; k += 4) {
                    float4 w = *(const float4*)(wh0 + k);
                    float4 x = *(const float4*)(hr + k);
                    FMA4(a4, w, x);
                }
            }
            gl[b][jl] = (a4.x + a4.y) + (a4.z + a4.w) + bias0;
        }
        __syncthreads();
        if (tid < 128) {
            const int bb = tid >> 2, q = tid & 3;
            float gi = gl[bb][q], gf = gl[bb][4 + q], gg = gl[bb][8 + q], go = gl[bb][12 + q];
            float c = sigmoidf_(gf) * cst0[bb][q] + sigmoidf_(gi) * tanhf(gg);
            float h = sigmoidf_(go) * tanhf(c);
            cst0[bb][q] = c;
            h0_buf[((size_t)(t & 1) * B + bb) * H + bk * 4 + q] = h;
        }
        __threadfence();
        grid.sync();

        // ---- Phase B: layer-1 gates ----
        {
            float4 a4 = make_float4(0.f, 0.f, 0.f, 0.f);
            const float* xr = h0_buf + ((size_t)(t & 1) * B + b) * H;
            #pragma unroll 4
            for (int k = 0; k < 1024; k += 4) {
                float4 w = *(const float4*)(wi1 + k);
                float4 x = *(const float4*)(xr + k);
                FMA4(a4, w, x);
            }
            if (t > 0) {
                const float* hr = h1_buf + ((size_t)((t - 1) & 1) * B + b) * H;
                #pragma unroll 4
                for (int k = 0; k < 1024; k += 4) {
                    float4 w = *(const float4*)(wh1 + k);
                    float4 x = *(const float4*)(hr + k);
                    FMA4(a4, w, x);
                }
            }
            gl[b][jl] = (a4.x + a4.y) + (a4.z + a4.w) + bias1;
        }
        __syncthreads();
        if (tid < 128) {
            const int bb = tid >> 2, q = tid & 3;
            float gi = gl[bb][q], gf = gl[bb][4 + q], gg = gl[bb][8 + q], go = gl[bb][12 + q];
            float c = sigmoidf_(gf) * cst1[bb][q] + sigmoidf_(gi) * tanhf(gg);
            float h = sigmoidf_(go) * tanhf(c);
            cst1[bb][q] = c;
            h1_buf[((size_t)(t & 1) * B + bb) * H + bk * 4 + q] = h;
        }
        __threadfence();
        grid.sync();
    }

    // ---- Epilogue: projection h-part for the last timestep ----
    if (gid < 2560) {
        const float* hrow = h1_buf + ((size_t)((T - 1) & 1) * B + pb) * H;
        float4 s4 = make_float4(0.f, 0.f, 0.f, 0.f);
        #pragma unroll
        for (int i = 0; i < 8; ++i) {
            const int k = lane * 4 + i * 128;
            float4 w = *(const float4*)(wp_row + k);
            float4 x = *(const float4*)(hrow + k);
            FMA4(s4, w, x);
        }
        float s = (s4.x + s4.y) + (s4.z + s4.w);
        s += __shfl_xor(s, 16); s += __shfl_xor(s, 8);
        s += __shfl_xor(s, 4);  s += __shfl_xor(s, 2); s += __shfl_xor(s, 1);
        if (lane == 0) out[((size_t)pb * T + (T - 1)) * 80 + po] += s;
    }
}

extern "C" void kernel_launch(void* const* d_in, const int* in_sizes, int n_in,
                              void* d_out, int out_size, void* d_ws, size_t ws_size,
                              hipStream_t stream)
{
    const float* memory = (const float*)d_in[0];   // [32][1000][512]
    const float* y_mels = (const float*)d_in[1];   // [32][1000][80]
    const float* W1     = (const float*)d_in[2];   // [256][80]
    const float* W2     = (const float*)d_in[3];   // [256][256]
    const float* w_ih0  = (const float*)d_in[4];   // [4096][768]
    const float* w_hh0  = (const float*)d_in[5];   // [4096][1024]
    const float* b_ih0  = (const float*)d_in[6];
    const float* b_hh0  = (const float*)d_in[7];
    const float* w_ih1  = (const float*)d_in[8];   // [4096][1024]
    const float* w_hh1  = (const float*)d_in[9];   // [4096][1024]
    const float* b_ih1  = (const float*)d_in[10];
    const float* b_hh1  = (const float*)d_in[11];
    const float* Wp     = (const float*)d_in[12];  // [80][1536]
    const float* bp     = (const float*)d_in[13];  // [80]
    float* out = (float*)d_out;

    const int B = 32, T = 1000;

    float* ws = (float*)d_ws;
    float* p2     = ws;                              // [T][B][256]   (32.8 MB)
    float* h0_buf = p2 + (size_t)T * B * 256;        // [2][B][1024]  (0.25 MB)
    float* h1_buf = h0_buf + 2 * B * 1024;           // [2][B][1024]  (0.25 MB)

    prenet_kernel<<<T * B, 256, 0, stream>>>(y_mels, W1, W2, p2, T);
    proj_mem_kernel<<<B * T, 128, 0, stream>>>(memory, Wp, bp, out, T);

    {
        int Tt = T;
        void* args[] = { (void*)&p2, (void*)&memory,
                         (void*)&w_ih0, (void*)&w_hh0, (void*)&b_ih0, (void*)&b_hh0,
                         (void*)&w_ih1, (void*)&w_hh1, (void*)&b_ih1, (void*)&b_hh1,
                         (void*)&Wp, (void*)&h0_buf, (void*)&h1_buf, (void*)&out, (void*)&Tt };
        hipLaunchCooperativeKernel((void*)fused_scan, dim3(256), dim3(512), args, 0, stream);
    }
}

// Round 4
// 82166.986 us; speedup vs baseline: 4.7463x; 4.7463x over previous
//
#include <hip/hip_runtime.h>
#include <hip/hip_cooperative_groups.h>
#include <cstddef>

namespace cg = cooperative_groups;

typedef __attribute__((ext_vector_type(8))) short short8v;   // 8 bf16 = 4 VGPRs
typedef __attribute__((ext_vector_type(4))) float float4v;   // MFMA acc

__device__ __forceinline__ float sigmoidf_(float x) {
    return 1.0f / (1.0f + __expf(-x));
}

__device__ __forceinline__ short f2bf(float f) {   // fp32 -> bf16 (RNE)
    union { float f; unsigned u; } v; v.f = f;
    unsigned r = (v.u + 0x7fffu + ((v.u >> 16) & 1u)) >> 16;
    return (short)r;
}

__device__ __forceinline__ float bfhi2f(unsigned bits_in_high) {  // bf16 bits already at [31:16]
    union { unsigned u; float f; } v; v.u = bits_in_high; return v.f;
}

__device__ __forceinline__ short8v pack8(float4 a, float4 b) {
    short8v r;
    r[0] = f2bf(a.x); r[1] = f2bf(a.y); r[2] = f2bf(a.z); r[3] = f2bf(a.w);
    r[4] = f2bf(b.x); r[5] = f2bf(b.y); r[6] = f2bf(b.z); r[7] = f2bf(b.w);
    return r;
}

#define FMA4(a4, w, x) \
    do { a4.x += (w).x*(x).x; a4.y += (w).y*(x).y; a4.z += (w).z*(x).z; a4.w += (w).w*(x).w; } while (0)

// ---------------- Prenet: p2 = relu(relu(prev @ W1^T) @ W2^T) ----------------
__global__ __launch_bounds__(256) void prenet_kernel(
    const float* __restrict__ y_mels,   // [B][T][80]
    const float* __restrict__ W1,       // [256][80]
    const float* __restrict__ W2,       // [256][256]
    float* __restrict__ p2,             // [T][B][256]
    int T)
{
    const int rt = blockIdx.x;           // t*32 + b
    const int t = rt >> 5, b = rt & 31;
    const int j = threadIdx.x;           // 0..255
    __shared__ float prev[80];
    __shared__ float p1[256];
    if (j < 80) prev[j] = (t == 0) ? 0.0f : y_mels[((size_t)b * T + (t - 1)) * 80 + j];
    __syncthreads();
    float acc = 0.0f;
    const float* w1r = W1 + j * 80;
    #pragma unroll
    for (int k = 0; k < 80; k += 4) {
        float4 w = *(const float4*)(w1r + k);
        float4 x = *(const float4*)(&prev[k]);
        acc += w.x * x.x + w.y * x.y + w.z * x.z + w.w * x.w;
    }
    p1[j] = fmaxf(acc, 0.0f);
    __syncthreads();
    float4 a4 = make_float4(0.f, 0.f, 0.f, 0.f);
    const float* w2r = W2 + j * 256;
    #pragma unroll 8
    for (int k = 0; k < 256; k += 4) {
        float4 w = *(const float4*)(w2r + k);
        float4 x = *(const float4*)(&p1[k]);
        FMA4(a4, w, x);
    }
    p2[(size_t)rt * 256 + j] = fmaxf((a4.x + a4.y) + (a4.z + a4.w), 0.0f);
}

// ------------- Projection, memory part: out[b,t,o] = bp[o] + mem[b,t,:]·Wp[o,1024:] -------------
__global__ __launch_bounds__(128) void proj_mem_kernel(
    const float* __restrict__ memory, // [B][T][512]
    const float* __restrict__ Wp,     // [80][1536]
    const float* __restrict__ bp,     // [80]
    float* __restrict__ out,          // [B][T][80]
    int T)
{
    const int rt = blockIdx.x;
    const int tid = threadIdx.x;
    __shared__ float xm[512];
    for (int k = tid * 4; k < 512; k += 128 * 4)
        *(float4*)(&xm[k]) = *(const float4*)(memory + (size_t)rt * 512 + k);
    __syncthreads();
    if (tid < 80) {
        const float* wr = Wp + tid * 1536 + 1024;
        float4 a4 = make_float4(0.f, 0.f, 0.f, 0.f);
        #pragma unroll 8
        for (int k = 0; k < 512; k += 4) {
            float4 w = *(const float4*)(wr + k);
            float4 x = *(const float4*)(&xm[k]);
            FMA4(a4, w, x);
        }
        out[(size_t)rt * 80 + tid] = bp[tid] + (a4.x + a4.y) + (a4.z + a4.w);
    }
}

// ================= Persistent-weight MFMA scan =================
// 256 blocks x 512 threads (8 waves). Block bk owns gate columns
// j(jl) = (jl>>2)*1024 + bk*4 + (jl&3), jl in [0,16), for BOTH layers.
// Recurrent+input weights live in VGPRs as bf16 MFMA B-frags (wave w owns
// k-slice [w*128,(w+1)*128) of K=1024 mats; [w*96,+96) of K=768).
// Software pipeline per phase t: L0 computes h0[t]; L1 computes h1[t-1];
// proj consumes h1[t-2]. One grid.sync per phase.
__global__ __launch_bounds__(512, 2) void fused_scan_mfma(
    const float* __restrict__ p2,     // [T][B][256]
    const float* __restrict__ memory, // [B][T][512]
    const float* __restrict__ w_ih0,  // [4096][768]
    const float* __restrict__ w_hh0,  // [4096][1024]
    const float* __restrict__ b_ih0,
    const float* __restrict__ b_hh0,
    const float* __restrict__ w_ih1,  // [4096][1024]
    const float* __restrict__ w_hh1,  // [4096][1024]
    const float* __restrict__ b_ih1,
    const float* __restrict__ b_hh1,
    const float* __restrict__ Wp,     // [80][1536]
    unsigned short* __restrict__ hb0, // [2][32][1024] bf16 ping-pong
    unsigned short* __restrict__ hb1, // [2][32][1024] bf16 ping-pong
    float* __restrict__ out,          // [B][T][80] (pre-filled with mem part)
    int T)
{
    const int bk  = blockIdx.x;
    const int tid = threadIdx.x;
    const int wave = tid >> 6;
    const int lane = tid & 63;
    const int col  = lane & 15;          // MFMA col (n) / A row (m)
    const int oct  = (lane >> 4) & 3;    // k-octet selector
    const int jcol = ((col >> 2) * 1024) + bk * 4 + (col & 3);  // gate row in [0,4096)

    // ---- persistent weight fragments (loaded once, fp32 -> bf16) ----
    const float* wr_i0 = w_ih0 + (size_t)jcol * 768;
    const float* wr_h0 = w_hh0 + (size_t)jcol * 1024;
    const float* wr_i1 = w_ih1 + (size_t)jcol * 1024;
    const float* wr_h1 = w_hh1 + (size_t)jcol * 1024;
    short8v wf_i0[3], wf_h0[4], wf_i1[4], wf_h1[4];
    #pragma unroll
    for (int s = 0; s < 3; ++s) {
        int k = wave * 96 + s * 32 + oct * 8;
        wf_i0[s] = pack8(*(const float4*)(wr_i0 + k), *(const float4*)(wr_i0 + k + 4));
    }
    #pragma unroll
    for (int s = 0; s < 4; ++s) {
        int k = wave * 128 + s * 32 + oct * 8;
        wf_h0[s] = pack8(*(const float4*)(wr_h0 + k), *(const float4*)(wr_h0 + k + 4));
        wf_i1[s] = pack8(*(const float4*)(wr_i1 + k), *(const float4*)(wr_i1 + k + 4));
        wf_h1[s] = pack8(*(const float4*)(wr_h1 + k), *(const float4*)(wr_h1 + k + 4));
    }

    // ---- LDS ----
    __shared__ float red[8][4][16][16];  // per-wave partial tiles
    __shared__ float gl2[2][32][16];     // reduced gates
    __shared__ float cst[2][32][4];      // cell states (block's 4 cells x 2 layers)
    __shared__ float bias_l[2][16];
    if (tid < 32) {
        int ly = tid >> 4, jl = tid & 15;
        int j = ((jl >> 2) * 1024) + bk * 4 + (jl & 3);
        bias_l[ly][jl] = ly ? (b_ih1[j] + b_hh1[j]) : (b_ih0[j] + b_hh0[j]);
    }
    if (tid < 256) cst[tid >> 7][(tid >> 2) & 31][tid & 3] = 0.0f;

    // ---- persistent projection weights: group gid handles out[pb][.][po] ----
    const int gid = bk * 16 + (tid >> 5);
    const int lane32 = tid & 31;
    const int pb = gid / 80, po = gid - pb * 80;
    float wp[32];
    if (gid < 2560) {
        #pragma unroll
        for (int i = 0; i < 8; ++i) {
            float4 w = *(const float4*)(Wp + (size_t)po * 1536 + lane32 * 4 + i * 128);
            wp[i*4+0] = w.x; wp[i*4+1] = w.y; wp[i*4+2] = w.z; wp[i*4+3] = w.w;
        }
    }

    // ---- zero h ping-pong buffers (256 KB total, 65536 u32) ----
    {
        int idx = bk * 512 + tid;
        if (idx < 65536) ((unsigned int*)hb0)[idx] = 0u;
    }

    cg::grid_group grid = cg::this_grid();
    __threadfence();
    grid.sync();

    for (int t = 0; t <= T + 1; ++t) {
        const bool doL0 = (t < T);
        const bool doL1 = (t >= 1) && (t <= T);
        float4v acc0[2], acc1[2];
        #pragma unroll
        for (int mt = 0; mt < 2; ++mt) {
            acc0[mt] = (float4v){0.f, 0.f, 0.f, 0.f};
            acc1[mt] = (float4v){0.f, 0.f, 0.f, 0.f};
        }
        const unsigned short* h0prev  = hb0 + (size_t)((t + 1) & 1) * 32768;  // h0[t-1]
        const unsigned short* h1prev2 = hb1 + (size_t)(t & 1) * 32768;        // h1[t-2]

        // ---- L0 input GEMM: x = [p2 | memory], K=768 ----
        if (doL0) {
            #pragma unroll
            for (int s = 0; s < 3; ++s) {
                int kb = wave * 96 + s * 32;
                int kk = kb + oct * 8;
                short8v a0, a1;
                if (kb < 256) {
                    const float* s0 = p2 + ((size_t)t * 32 + col) * 256 + kk;
                    const float* s1 = p2 + ((size_t)t * 32 + col + 16) * 256 + kk;
                    a0 = pack8(*(const float4*)s0, *(const float4*)(s0 + 4));
                    a1 = pack8(*(const float4*)s1, *(const float4*)(s1 + 4));
                } else {
                    const float* s0 = memory + ((size_t)col * T + t) * 512 + (kk - 256);
                    const float* s1 = memory + ((size_t)(col + 16) * T + t) * 512 + (kk - 256);
                    a0 = pack8(*(const float4*)s0, *(const float4*)(s0 + 4));
                    a1 = pack8(*(const float4*)s1, *(const float4*)(s1 + 4));
                }
                acc0[0] = __builtin_amdgcn_mfma_f32_16x16x32_bf16(a0, wf_i0[s], acc0[0], 0, 0, 0);
                acc0[1] = __builtin_amdgcn_mfma_f32_16x16x32_bf16(a1, wf_i0[s], acc0[1], 0, 0, 0);
            }
        }
        // ---- h0[t-1]-driven GEMMs: whh0 (L0) and wih1 (L1) share A-frags ----
        if (doL0 || doL1) {
            #pragma unroll
            for (int s = 0; s < 4; ++s) {
                int kk = wave * 128 + s * 32 + oct * 8;
                short8v a0 = *(const short8v*)(h0prev + (size_t)col * 1024 + kk);
                short8v a1 = *(const short8v*)(h0prev + (size_t)(col + 16) * 1024 + kk);
                if (doL0) {
                    acc0[0] = __builtin_amdgcn_mfma_f32_16x16x32_bf16(a0, wf_h0[s], acc0[0], 0, 0, 0);
                    acc0[1] = __builtin_amdgcn_mfma_f32_16x16x32_bf16(a1, wf_h0[s], acc0[1], 0, 0, 0);
                }
                if (doL1) {
                    acc1[0] = __builtin_amdgcn_mfma_f32_16x16x32_bf16(a0, wf_i1[s], acc1[0], 0, 0, 0);
                    acc1[1] = __builtin_amdgcn_mfma_f32_16x16x32_bf16(a1, wf_i1[s], acc1[1], 0, 0, 0);
                }
            }
            if (doL1) {
                #pragma unroll
                for (int s = 0; s < 4; ++s) {
                    int kk = wave * 128 + s * 32 + oct * 8;
                    short8v a0 = *(const short8v*)(h1prev2 + (size_t)col * 1024 + kk);
                    short8v a1 = *(const short8v*)(h1prev2 + (size_t)(col + 16) * 1024 + kk);
                    acc1[0] = __builtin_amdgcn_mfma_f32_16x16x32_bf16(a0, wf_h1[s], acc1[0], 0, 0, 0);
                    acc1[1] = __builtin_amdgcn_mfma_f32_16x16x32_bf16(a1, wf_h1[s], acc1[1], 0, 0, 0);
                }
            }
        }
        // ---- cross-wave k-reduction ----
        if (doL0) {
            #pragma unroll
            for (int mt = 0; mt < 2; ++mt)
                #pragma unroll
                for (int r = 0; r < 4; ++r)
                    red[wave][mt][oct * 4 + r][col] = acc0[mt][r];
        }
        if (doL1) {
            #pragma unroll
            for (int mt = 0; mt < 2; ++mt)
                #pragma unroll
                for (int r = 0; r < 4; ++r)
                    red[wave][2 + mt][oct * 4 + r][col] = acc1[mt][r];
        }
        __syncthreads();
        #pragma unroll
        for (int e = tid; e < 1024; e += 512) {
            int tt = e >> 8, m = (e >> 4) & 15, n = e & 15;
            int ly = tt >> 1;
            if (ly ? doL1 : doL0) {
                float s = 0.f;
                #pragma unroll
                for (int w = 0; w < 8; ++w) s += red[w][tt][m][n];
                gl2[ly][(tt & 1) * 16 + m][n] = s + bias_l[ly][n];
            }
        }
        __syncthreads();
        // ---- activations: 256 tasks = 2 layers x 32 b x 4 cells ----
        if (tid < 256) {
            int ly = tid >> 7, rem = tid & 127, bb = rem >> 2, cl = rem & 3;
            if (ly ? doL1 : doL0) {
                float gi = gl2[ly][bb][cl];
                float gf = gl2[ly][bb][4 + cl];
                float gg = gl2[ly][bb][8 + cl];
                float go = gl2[ly][bb][12 + cl];
                float c = sigmoidf_(gf) * cst[ly][bb][cl] + sigmoidf_(gi) * tanhf(gg);
                float h = sigmoidf_(go) * tanhf(c);
                cst[ly][bb][cl] = c;
                unsigned short hv = (unsigned short)f2bf(h);
                if (ly == 0) hb0[(size_t)(t & 1) * 32768 + bb * 1024 + bk * 4 + cl] = hv;       // h0[t]
                else         hb1[(size_t)((t + 1) & 1) * 32768 + bb * 1024 + bk * 4 + cl] = hv; // h1[t-1]
            }
        }
        // ---- projection h-part for row t-2 (reads h1[t-2], slot t&1) ----
        if (t >= 2 && gid < 2560) {
            const unsigned short* hrow = h1prev2 + (size_t)pb * 1024;
            float sum = 0.f;
            #pragma unroll
            for (int i = 0; i < 8; ++i) {
                int k = lane32 * 4 + i * 128;
                uint2 hv = *(const uint2*)(hrow + k);
                float x0 = bfhi2f(hv.x << 16);
                float x1 = bfhi2f(hv.x & 0xffff0000u);
                float x2 = bfhi2f(hv.y << 16);
                float x3 = bfhi2f(hv.y & 0xffff0000u);
                sum += wp[i*4+0]*x0 + wp[i*4+1]*x1 + wp[i*4+2]*x2 + wp[i*4+3]*x3;
            }
            sum += __shfl_xor(sum, 16);
            sum += __shfl_xor(sum, 8);
            sum += __shfl_xor(sum, 4);
            sum += __shfl_xor(sum, 2);
            sum += __shfl_xor(sum, 1);
            if (lane32 == 0) {
                float* op = out + ((size_t)pb * T + (t - 2)) * 80 + po;
                *op += sum;
            }
        }
        __threadfence();
        grid.sync();
    }
}

extern "C" void kernel_launch(void* const* d_in, const int* in_sizes, int n_in,
                              void* d_out, int out_size, void* d_ws, size_t ws_size,
                              hipStream_t stream)
{
    const float* memory = (const float*)d_in[0];   // [32][1000][512]
    const float* y_mels = (const float*)d_in[1];   // [32][1000][80]
    const float* W1     = (const float*)d_in[2];   // [256][80]
    const float* W2     = (const float*)d_in[3];   // [256][256]
    const float* w_ih0  = (const float*)d_in[4];   // [4096][768]
    const float* w_hh0  = (const float*)d_in[5];   // [4096][1024]
    const float* b_ih0  = (const float*)d_in[6];
    const float* b_hh0  = (const float*)d_in[7];
    const float* w_ih1  = (const float*)d_in[8];   // [4096][1024]
    const float* w_hh1  = (const float*)d_in[9];   // [4096][1024]
    const float* b_ih1  = (const float*)d_in[10];
    const float* b_hh1  = (const float*)d_in[11];
    const float* Wp     = (const float*)d_in[12];  // [80][1536]
    const float* bp     = (const float*)d_in[13];  // [80]
    float* out = (float*)d_out;

    const int B = 32, T = 1000;

    float* ws = (float*)d_ws;
    float* p2 = ws;                                        // [T][B][256] fp32 (32.8 MB)
    unsigned short* hb0 = (unsigned short*)(p2 + (size_t)T * B * 256);  // [2][32][1024] bf16
    unsigned short* hb1 = hb0 + 2 * 32 * 1024;                          // [2][32][1024] bf16

    prenet_kernel<<<T * B, 256, 0, stream>>>(y_mels, W1, W2, p2, T);
    proj_mem_kernel<<<B * T, 128, 0, stream>>>(memory, Wp, bp, out, T);

    {
        int Tt = T;
        void* args[] = { (void*)&p2, (void*)&memory,
                         (void*)&w_ih0, (void*)&w_hh0, (void*)&b_ih0, (void*)&b_hh0,
                         (void*)&w_ih1, (void*)&w_hh1, (void*)&b_ih1, (void*)&b_hh1,
                         (void*)&Wp, (void*)&hb0, (void*)&hb1, (void*)&out, (void*)&Tt };
        hipLaunchCooperativeKernel((void*)fused_scan_mfma, dim3(256), dim3(512), args, 0, stream);
    }
}

// Round 5
// 19102.603 us; speedup vs baseline: 20.4157x; 4.3014x over previous
//
#include <hip/hip_runtime.h>
#include <cstddef>

typedef __attribute__((ext_vector_type(8))) short short8v;   // 8 bf16 = 4 VGPRs
typedef __attribute__((ext_vector_type(4))) float float4v;   // MFMA acc

__device__ __forceinline__ float sigmoidf_(float x) {
    return 1.0f / (1.0f + __expf(-x));
}

__device__ __forceinline__ short f2bf(float f) {   // fp32 -> bf16 (RNE)
    union { float f; unsigned u; } v; v.f = f;
    unsigned r = (v.u + 0x7fffu + ((v.u >> 16) & 1u)) >> 16;
    return (short)r;
}

__device__ __forceinline__ float bfhi2f(unsigned bits_in_high) {  // bf16 bits at [31:16]
    union { unsigned u; float f; } v; v.u = bits_in_high; return v.f;
}

__device__ __forceinline__ short8v pack8(float4 a, float4 b) {
    short8v r;
    r[0] = f2bf(a.x); r[1] = f2bf(a.y); r[2] = f2bf(a.z); r[3] = f2bf(a.w);
    r[4] = f2bf(b.x); r[5] = f2bf(b.y); r[6] = f2bf(b.z); r[7] = f2bf(b.w);
    return r;
}

#define FMA4(a4, w, x) \
    do { a4.x += (w).x*(x).x; a4.y += (w).y*(x).y; a4.z += (w).z*(x).z; a4.w += (w).w*(x).w; } while (0)

// ---------------- Prenet ----------------
__global__ __launch_bounds__(256) void prenet_kernel(
    const float* __restrict__ y_mels,   // [B][T][80]
    const float* __restrict__ W1,       // [256][80]
    const float* __restrict__ W2,       // [256][256]
    float* __restrict__ p2,             // [T][B][256]
    int T)
{
    const int rt = blockIdx.x;           // t*32 + b
    const int t = rt >> 5, b = rt & 31;
    const int j = threadIdx.x;           // 0..255
    __shared__ float prev[80];
    __shared__ float p1[256];
    if (j < 80) prev[j] = (t == 0) ? 0.0f : y_mels[((size_t)b * T + (t - 1)) * 80 + j];
    __syncthreads();
    float acc = 0.0f;
    const float* w1r = W1 + j * 80;
    #pragma unroll
    for (int k = 0; k < 80; k += 4) {
        float4 w = *(const float4*)(w1r + k);
        float4 x = *(const float4*)(&prev[k]);
        acc += w.x * x.x + w.y * x.y + w.z * x.z + w.w * x.w;
    }
    p1[j] = fmaxf(acc, 0.0f);
    __syncthreads();
    float4 a4 = make_float4(0.f, 0.f, 0.f, 0.f);
    const float* w2r = W2 + j * 256;
    #pragma unroll 8
    for (int k = 0; k < 256; k += 4) {
        float4 w = *(const float4*)(w2r + k);
        float4 x = *(const float4*)(&p1[k]);
        FMA4(a4, w, x);
    }
    p2[(size_t)rt * 256 + j] = fmaxf((a4.x + a4.y) + (a4.z + a4.w), 0.0f);
}

// ------------- Projection, memory part -------------
__global__ __launch_bounds__(128) void proj_mem_kernel(
    const float* __restrict__ memory, // [B][T][512]
    const float* __restrict__ Wp,     // [80][1536]
    const float* __restrict__ bp,     // [80]
    float* __restrict__ out,          // [B][T][80]
    int T)
{
    const int rt = blockIdx.x;
    const int tid = threadIdx.x;
    __shared__ float xm[512];
    for (int k = tid * 4; k < 512; k += 128 * 4)
        *(float4*)(&xm[k]) = *(const float4*)(memory + (size_t)rt * 512 + k);
    __syncthreads();
    if (tid < 80) {
        const float* wr = Wp + tid * 1536 + 1024;
        float4 a4 = make_float4(0.f, 0.f, 0.f, 0.f);
        #pragma unroll 8
        for (int k = 0; k < 512; k += 4) {
            float4 w = *(const float4*)(wr + k);
            float4 x = *(const float4*)(&xm[k]);
            FMA4(a4, w, x);
        }
        out[(size_t)rt * 80 + tid] = bp[tid] + (a4.x + a4.y) + (a4.z + a4.w);
    }
}

// ================= Persistent-weight MFMA scan, custom barrier =================
// 256 blocks x 512 threads. Same work decomposition as round 4. Replaces
// cg::grid.sync with a 2-level monotonic arrive/wait barrier; proj + next-step
// input GEMM execute in the arrive->wait window. h1 is quad-buffered.
__global__ __launch_bounds__(512, 2) void fused_scan_mfma(
    const float* __restrict__ p2,     // [T][B][256]
    const float* __restrict__ memory, // [B][T][512]
    const float* __restrict__ w_ih0,  // [4096][768]
    const float* __restrict__ w_hh0,  // [4096][1024]
    const float* __restrict__ b_ih0,
    const float* __restrict__ b_hh0,
    const float* __restrict__ w_ih1,  // [4096][1024]
    const float* __restrict__ w_hh1,  // [4096][1024]
    const float* __restrict__ b_ih1,
    const float* __restrict__ b_hh1,
    const float* __restrict__ Wp,     // [80][1536]
    unsigned short* __restrict__ hb0, // [2][32][1024] bf16 (memset 0)
    unsigned short* __restrict__ hb1, // [4][32][1024] bf16 (memset 0)
    float* __restrict__ out,          // [B][T][80] (pre-filled with mem part)
    unsigned* __restrict__ bar,       // [16 groups *64 | root at +1024] (memset 0)
    int T)
{
    const int bk  = blockIdx.x;
    const int tid = threadIdx.x;
    const int wave = tid >> 6;
    const int lane = tid & 63;
    const int col  = lane & 15;          // MFMA col (n) / A row (m)
    const int oct  = (lane >> 4) & 3;    // k-octet selector
    const int jcol = ((col >> 2) * 1024) + bk * 4 + (col & 3);

    // ---- persistent weight fragments ----
    const float* wr_i0 = w_ih0 + (size_t)jcol * 768;
    const float* wr_h0 = w_hh0 + (size_t)jcol * 1024;
    const float* wr_i1 = w_ih1 + (size_t)jcol * 1024;
    const float* wr_h1 = w_hh1 + (size_t)jcol * 1024;
    short8v wf_i0[3], wf_h0[4], wf_i1[4], wf_h1[4];
    #pragma unroll
    for (int s = 0; s < 3; ++s) {
        int k = wave * 96 + s * 32 + oct * 8;
        wf_i0[s] = pack8(*(const float4*)(wr_i0 + k), *(const float4*)(wr_i0 + k + 4));
    }
    #pragma unroll
    for (int s = 0; s < 4; ++s) {
        int k = wave * 128 + s * 32 + oct * 8;
        wf_h0[s] = pack8(*(const float4*)(wr_h0 + k), *(const float4*)(wr_h0 + k + 4));
        wf_i1[s] = pack8(*(const float4*)(wr_i1 + k), *(const float4*)(wr_i1 + k + 4));
        wf_h1[s] = pack8(*(const float4*)(wr_h1 + k), *(const float4*)(wr_h1 + k + 4));
    }

    // ---- LDS ----
    __shared__ float red[8][4][16][16];
    __shared__ float gl2[2][32][16];
    __shared__ float cst[2][32][4];
    __shared__ float bias_l[2][16];
    if (tid < 32) {
        int ly = tid >> 4, jl = tid & 15;
        int j = ((jl >> 2) * 1024) + bk * 4 + (jl & 3);
        bias_l[ly][jl] = ly ? (b_ih1[j] + b_hh1[j]) : (b_ih0[j] + b_hh0[j]);
    }
    if (tid < 256) cst[tid >> 7][(tid >> 2) & 31][tid & 3] = 0.0f;

    // ---- persistent projection weights ----
    const int gid = bk * 16 + (tid >> 5);
    const int lane32 = tid & 31;
    const int pb = gid / 80, po = gid - pb * 80;
    float wp[32];
    if (gid < 2560) {
        #pragma unroll
        for (int i = 0; i < 8; ++i) {
            float4 w = *(const float4*)(Wp + (size_t)po * 1536 + lane32 * 4 + i * 128);
            wp[i*4+0] = w.x; wp[i*4+1] = w.y; wp[i*4+2] = w.z; wp[i*4+3] = w.w;
        }
    }

    unsigned* grp_cnt  = bar + (bk >> 4) * 64;
    unsigned* root_cnt = bar + 1024;

    // ---- input GEMM lambda (x = [p2 | memory], K=768) ----
    auto input_gemm = [&](int tt, float4v* acc) {
        #pragma unroll
        for (int s = 0; s < 3; ++s) {
            int kb = wave * 96 + s * 32;
            int kk = kb + oct * 8;
            short8v a0, a1;
            if (kb < 256) {
                const float* s0 = p2 + ((size_t)tt * 32 + col) * 256 + kk;
                const float* s1 = p2 + ((size_t)tt * 32 + col + 16) * 256 + kk;
                a0 = pack8(*(const float4*)s0, *(const float4*)(s0 + 4));
                a1 = pack8(*(const float4*)s1, *(const float4*)(s1 + 4));
            } else {
                const float* s0 = memory + ((size_t)col * T + tt) * 512 + (kk - 256);
                const float* s1 = memory + ((size_t)(col + 16) * T + tt) * 512 + (kk - 256);
                a0 = pack8(*(const float4*)s0, *(const float4*)(s0 + 4));
                a1 = pack8(*(const float4*)s1, *(const float4*)(s1 + 4));
            }
            acc[0] = __builtin_amdgcn_mfma_f32_16x16x32_bf16(a0, wf_i0[s], acc[0], 0, 0, 0);
            acc[1] = __builtin_amdgcn_mfma_f32_16x16x32_bf16(a1, wf_i0[s], acc[1], 0, 0, 0);
        }
    };

    __syncthreads();

    // prologue: input GEMM for t=0 (p2 ready by stream order; no barrier needed)
    float4v acc0[2];
    acc0[0] = (float4v){0.f, 0.f, 0.f, 0.f};
    acc0[1] = (float4v){0.f, 0.f, 0.f, 0.f};
    if (T > 0) input_gemm(0, acc0);

    for (int t = 0; t <= T + 1; ++t) {
        // ---- wait for barrier t-1 ----
        if (t > 0) {
            if (tid == 0) {
                while (__hip_atomic_load(root_cnt, __ATOMIC_RELAXED, __HIP_MEMORY_SCOPE_AGENT)
                       < 16u * (unsigned)t) { }
                (void)__hip_atomic_load(root_cnt, __ATOMIC_ACQUIRE, __HIP_MEMORY_SCOPE_AGENT);
            }
            __syncthreads();
        }

        const bool doL0 = (t < T);
        const bool doL1 = (t >= 1) && (t <= T);
        float4v acc1[2];
        acc1[0] = (float4v){0.f, 0.f, 0.f, 0.f};
        acc1[1] = (float4v){0.f, 0.f, 0.f, 0.f};
        const unsigned short* h0prev  = hb0 + (size_t)((t + 1) & 1) * 32768;   // h0[t-1]
        const unsigned short* h1prev2 = hb1 + (size_t)((t - 2) & 3) * 32768;   // h1[t-2]

        // ---- h0[t-1]-driven GEMMs ----
        if (doL0 || doL1) {
            #pragma unroll
            for (int s = 0; s < 4; ++s) {
                int kk = wave * 128 + s * 32 + oct * 8;
                short8v a0 = *(const short8v*)(h0prev + (size_t)col * 1024 + kk);
                short8v a1 = *(const short8v*)(h0prev + (size_t)(col + 16) * 1024 + kk);
                if (doL0) {
                    acc0[0] = __builtin_amdgcn_mfma_f32_16x16x32_bf16(a0, wf_h0[s], acc0[0], 0, 0, 0);
                    acc0[1] = __builtin_amdgcn_mfma_f32_16x16x32_bf16(a1, wf_h0[s], acc0[1], 0, 0, 0);
                }
                if (doL1) {
                    acc1[0] = __builtin_amdgcn_mfma_f32_16x16x32_bf16(a0, wf_i1[s], acc1[0], 0, 0, 0);
                    acc1[1] = __builtin_amdgcn_mfma_f32_16x16x32_bf16(a1, wf_i1[s], acc1[1], 0, 0, 0);
                }
            }
            if (doL1) {
                #pragma unroll
                for (int s = 0; s < 4; ++s) {
                    int kk = wave * 128 + s * 32 + oct * 8;
                    short8v a0 = *(const short8v*)(h1prev2 + (size_t)col * 1024 + kk);
                    short8v a1 = *(const short8v*)(h1prev2 + (size_t)(col + 16) * 1024 + kk);
                    acc1[0] = __builtin_amdgcn_mfma_f32_16x16x32_bf16(a0, wf_h1[s], acc1[0], 0, 0, 0);
                    acc1[1] = __builtin_amdgcn_mfma_f32_16x16x32_bf16(a1, wf_h1[s], acc1[1], 0, 0, 0);
                }
            }
        }
        // ---- cross-wave k-reduction ----
        if (doL0) {
            #pragma unroll
            for (int mt = 0; mt < 2; ++mt)
                #pragma unroll
                for (int r = 0; r < 4; ++r)
                    red[wave][mt][oct * 4 + r][col] = acc0[mt][r];
        }
        if (doL1) {
            #pragma unroll
            for (int mt = 0; mt < 2; ++mt)
                #pragma unroll
                for (int r = 0; r < 4; ++r)
                    red[wave][2 + mt][oct * 4 + r][col] = acc1[mt][r];
        }
        __syncthreads();
        #pragma unroll
        for (int e = tid; e < 1024; e += 512) {
            int tt = e >> 8, m = (e >> 4) & 15, n = e & 15;
            int ly = tt >> 1;
            if (ly ? doL1 : doL0) {
                float s = 0.f;
                #pragma unroll
                for (int w = 0; w < 8; ++w) s += red[w][tt][m][n];
                gl2[ly][(tt & 1) * 16 + m][n] = s + bias_l[ly][n];
            }
        }
        __syncthreads();
        // ---- activations ----
        if (tid < 256) {
            int ly = tid >> 7, rem = tid & 127, bb = rem >> 2, cl = rem & 3;
            if (ly ? doL1 : doL0) {
                float gi = gl2[ly][bb][cl];
                float gf = gl2[ly][bb][4 + cl];
                float gg = gl2[ly][bb][8 + cl];
                float go = gl2[ly][bb][12 + cl];
                float c = sigmoidf_(gf) * cst[ly][bb][cl] + sigmoidf_(gi) * tanhf(gg);
                float h = sigmoidf_(go) * tanhf(c);
                cst[ly][bb][cl] = c;
                unsigned short hv = (unsigned short)f2bf(h);
                if (ly == 0) hb0[(size_t)(t & 1) * 32768 + bb * 1024 + bk * 4 + cl] = hv;           // h0[t]
                else         hb1[(size_t)((t - 1) & 3) * 32768 + bb * 1024 + bk * 4 + cl] = hv;     // h1[t-1]
            }
        }
        __syncthreads();   // drain h stores (vmcnt) before publishing

        // ---- arrive(t): release our h writes ----
        if (tid == 0) {
            unsigned old = __hip_atomic_fetch_add(grp_cnt, 1u, __ATOMIC_ACQ_REL,
                                                  __HIP_MEMORY_SCOPE_AGENT);
            if (old == 16u * (unsigned)(t + 1) - 1u)
                __hip_atomic_fetch_add(root_cnt, 1u, __ATOMIC_ACQ_REL,
                                       __HIP_MEMORY_SCOPE_AGENT);
        }

        // ---- window: independent work overlapping barrier propagation ----
        // projection for row t-2 (h1[t-2] synced at barrier t-1; slot safe: quad-buffered)
        if (t >= 2 && gid < 2560) {
            const unsigned short* hrow = h1prev2 + (size_t)pb * 1024;
            float sum = 0.f;
            #pragma unroll
            for (int i = 0; i < 8; ++i) {
                int k = lane32 * 4 + i * 128;
                uint2 hv = *(const uint2*)(hrow + k);
                float x0 = bfhi2f(hv.x << 16);
                float x1 = bfhi2f(hv.x & 0xffff0000u);
                float x2 = bfhi2f(hv.y << 16);
                float x3 = bfhi2f(hv.y & 0xffff0000u);
                sum += wp[i*4+0]*x0 + wp[i*4+1]*x1 + wp[i*4+2]*x2 + wp[i*4+3]*x3;
            }
            sum += __shfl_xor(sum, 16);
            sum += __shfl_xor(sum, 8);
            sum += __shfl_xor(sum, 4);
            sum += __shfl_xor(sum, 2);
            sum += __shfl_xor(sum, 1);
            if (lane32 == 0) {
                float* op = out + ((size_t)pb * T + (t - 2)) * 80 + po;
                *op += sum;
            }
        }
        // next step's input GEMM (reads read-only p2/memory)
        acc0[0] = (float4v){0.f, 0.f, 0.f, 0.f};
        acc0[1] = (float4v){0.f, 0.f, 0.f, 0.f};
        if (t + 1 < T) input_gemm(t + 1, acc0);
    }
}

extern "C" void kernel_launch(void* const* d_in, const int* in_sizes, int n_in,
                              void* d_out, int out_size, void* d_ws, size_t ws_size,
                              hipStream_t stream)
{
    const float* memory = (const float*)d_in[0];   // [32][1000][512]
    const float* y_mels = (const float*)d_in[1];   // [32][1000][80]
    const float* W1     = (const float*)d_in[2];   // [256][80]
    const float* W2     = (const float*)d_in[3];   // [256][256]
    const float* w_ih0  = (const float*)d_in[4];   // [4096][768]
    const float* w_hh0  = (const float*)d_in[5];   // [4096][1024]
    const float* b_ih0  = (const float*)d_in[6];
    const float* b_hh0  = (const float*)d_in[7];
    const float* w_ih1  = (const float*)d_in[8];   // [4096][1024]
    const float* w_hh1  = (const float*)d_in[9];   // [4096][1024]
    const float* b_ih1  = (const float*)d_in[10];
    const float* b_hh1  = (const float*)d_in[11];
    const float* Wp     = (const float*)d_in[12];  // [80][1536]
    const float* bp     = (const float*)d_in[13];  // [80]
    float* out = (float*)d_out;

    const int B = 32, T = 1000;

    float* ws = (float*)d_ws;
    float* p2 = ws;                                               // [T][B][256] fp32
    unsigned short* hb0 = (unsigned short*)(p2 + (size_t)T * B * 256); // [2][32][1024] bf16
    unsigned short* hb1 = hb0 + 2 * 32 * 1024;                         // [4][32][1024] bf16
    unsigned* bar = (unsigned*)(hb1 + 4 * 32 * 1024);                  // 8 KB barrier state

    // zero h buffers + barrier counters (d_ws is poisoned 0xAA before every launch)
    hipMemsetAsync(hb0, 0, (size_t)(2 + 4) * 32 * 1024 * sizeof(unsigned short) + 8192, stream);

    prenet_kernel<<<T * B, 256, 0, stream>>>(y_mels, W1, W2, p2, T);
    proj_mem_kernel<<<B * T, 128, 0, stream>>>(memory, Wp, bp, out, T);

    {
        int Tt = T;
        void* args[] = { (void*)&p2, (void*)&memory,
                         (void*)&w_ih0, (void*)&w_hh0, (void*)&b_ih0, (void*)&b_hh0,
                         (void*)&w_ih1, (void*)&w_hh1, (void*)&b_ih1, (void*)&b_hh1,
                         (void*)&Wp, (void*)&hb0, (void*)&hb1, (void*)&out, (void*)&bar, (void*)&Tt };
        hipLaunchCooperativeKernel((void*)fused_scan_mfma, dim3(256), dim3(512), args, 0, stream);
    }
}